// Round 1
// baseline (391.320 us; speedup 1.0000x reference)
//
#include <hip/hip_runtime.h>

// BagRE: segment-mean over sorted bags + linear classifier, fused.
//   hidden [N=262144, H=256] f32, W [C=128, H=256] f32, b [C] f32,
//   bag_id [N] i32 (sorted)  ->  out [NUM_BAGS=8192, C=128] f32
//
// Memory-bound: 256 MB hidden read dominates (~40 us floor @ 6.78 TB/s
// measured-achievable). R2 theory: previous version ran 16 waves/CU
// (1024 blocks x 4 waves) -> latency-exposed streaming at ~60% BW.
// This version: 1 bag per wave, BPB=4, grid=2048 -> 8 blocks/CU,
// 32 waves/CU (full occupancy), __launch_bounds__(256,8) to cap VGPR<=64.
// Also: per-wave binary search (lanes 0/1 + shfl) removes the block-wide
// barrier before phase 1 -- waves start streaming hidden immediately.

#define NBAGS 8192
#define HDIM 256
#define CDIM 128
#define BPB 4  // bags per block == waves per block

__global__ __launch_bounds__(256, 8) void bagre_kernel(
    const float* __restrict__ hidden,
    const float* __restrict__ W,
    const float* __restrict__ b,
    const int* __restrict__ bag_id,
    float* __restrict__ out,
    int N)
{
    __shared__ __align__(16) float s_mean[BPB][HDIM];   // 4 KB
    __shared__ float s_part[2][BPB][CDIM];              // 4 KB

    const int t    = threadIdx.x;
    const int g0   = blockIdx.x * BPB;
    const int wid  = t >> 6;    // wave id == bag index within block
    const int lane = t & 63;

    // --- per-wave segment bounds: lanes 0,1 lower_bound(g0+wid+lane) ---
    // No block barrier needed: each wave resolves its own bounds and goes.
    int bound = 0;
    if (lane < 2) {
        const int target = g0 + wid + lane;
        int lo = 0, hi = N;
        while (lo < hi) {
            const int mid = (lo + hi) >> 1;
            if (bag_id[mid] < target) lo = mid + 1; else hi = mid;
        }
        bound = lo;
    }
    const int s = __shfl(bound, 0);
    const int e = __shfl(bound, 1);

    // --- phase 1: this wave streams its bag's rows; lane holds 4 cols ---
    // (64 lanes x float4 = full 256-col row -> one contiguous 1 KB
    // transaction per row; rows are 1KB-aligned by construction).
    const int col4 = lane << 2;

    float4 a0 = make_float4(0.f, 0.f, 0.f, 0.f);
    float4 a1 = a0, a2 = a0, a3 = a0;

    const float* __restrict__ p = hidden + (size_t)s * HDIM + col4;
    int r = s;
    for (; r + 4 <= e; r += 4, p += 4 * HDIM) {
        // 4 independent 16 B loads per lane -> 4 KB/wave in flight;
        // latency hiding comes from 32 waves/CU TLP.
        const float4 v0 = *(const float4*)(p + 0 * HDIM);
        const float4 v1 = *(const float4*)(p + 1 * HDIM);
        const float4 v2 = *(const float4*)(p + 2 * HDIM);
        const float4 v3 = *(const float4*)(p + 3 * HDIM);
        a0.x += v0.x; a0.y += v0.y; a0.z += v0.z; a0.w += v0.w;
        a1.x += v1.x; a1.y += v1.y; a1.z += v1.z; a1.w += v1.w;
        a2.x += v2.x; a2.y += v2.y; a2.z += v2.z; a2.w += v2.w;
        a3.x += v3.x; a3.y += v3.y; a3.z += v3.z; a3.w += v3.w;
    }
    for (; r < e; ++r, p += HDIM) {
        const float4 v0 = *(const float4*)p;
        a0.x += v0.x; a0.y += v0.y; a0.z += v0.z; a0.w += v0.w;
    }

    const int cnt = e - s;
    const float inv = 1.0f / (float)(cnt > 1 ? cnt : 1);
    float4 m;
    m.x = (a0.x + a1.x + a2.x + a3.x) * inv;
    m.y = (a0.y + a1.y + a2.y + a3.y) * inv;
    m.z = (a0.z + a1.z + a2.z + a3.z) * inv;
    m.w = (a0.w + a1.w + a2.w + a3.w) * inv;
    *(float4*)(&s_mean[wid][col4]) = m;

    __syncthreads();  // the ONLY phase-1 barrier

    // --- phase 2: logits = mean @ W^T + b, 4-bag register blocking ---
    // thread t: class c = t&127, K-half = t>>7. W value reused across 4
    // bags; hbase is wave-uniform -> s_mean reads are LDS broadcasts.
    const int c    = t & (CDIM - 1);
    const int half = t >> 7;
    const float* __restrict__ wrow = W + (size_t)c * HDIM + half * (HDIM / 2);

    float acc[BPB];
#pragma unroll
    for (int j = 0; j < BPB; ++j) acc[j] = 0.f;

    for (int hh = 0; hh < HDIM / 2; hh += 4) {
        const float4 wv = *(const float4*)(wrow + hh);
        const int hbase = half * (HDIM / 2) + hh;
#pragma unroll
        for (int j = 0; j < BPB; ++j) {
            acc[j] += s_mean[j][hbase + 0] * wv.x
                    + s_mean[j][hbase + 1] * wv.y
                    + s_mean[j][hbase + 2] * wv.z
                    + s_mean[j][hbase + 3] * wv.w;
        }
    }

#pragma unroll
    for (int j = 0; j < BPB; ++j) s_part[half][j][c] = acc[j];
    __syncthreads();

    for (int idx = t; idx < BPB * CDIM; idx += 256) {
        const int j  = idx >> 7;
        const int cc = idx & (CDIM - 1);
        out[(size_t)(g0 + j) * CDIM + cc] =
            s_part[0][j][cc] + s_part[1][j][cc] + b[cc];
    }
}

extern "C" void kernel_launch(void* const* d_in, const int* in_sizes, int n_in,
                              void* d_out, int out_size, void* d_ws, size_t ws_size,
                              hipStream_t stream) {
    const float* hidden = (const float*)d_in[0];
    const float* W      = (const float*)d_in[1];
    const float* b      = (const float*)d_in[2];
    const int*   bag_id = (const int*)d_in[3];
    float* out = (float*)d_out;
    const int N = in_sizes[3];  // 262144

    bagre_kernel<<<NBAGS / BPB, 256, 0, stream>>>(hidden, W, b, bag_id, out, N);
}